// Round 10
// baseline (266.844 us; speedup 1.0000x reference)
//
#include <hip/hip_runtime.h>
#include <hip/hip_fp16.h>

#define NF 128   // feature dim, fixed by the problem

typedef _Float16 half8 __attribute__((ext_vector_type(8)));
typedef float    floatx4 __attribute__((ext_vector_type(4)));

// ---------------- prep: zero cnt + convert/transpose W1,W2 to fp16 ----------------
__global__ __launch_bounds__(256) void prep_k(
    int* __restrict__ cnt, int n, int nb,
    const float* __restrict__ W1, const float* __restrict__ W2,
    __half* __restrict__ WT1, __half* __restrict__ WT2)
{
    int b = blockIdx.x;
    if (b < nb) {
        int i = b * 256 + threadIdx.x;
        if (i < n) cnt[i] = 0;
    } else {
        int idx = (b - nb) * 256 + threadIdx.x;   // 0..32767
        const float* W = (idx < 16384) ? W1 : W2;
        __half* WT     = (idx < 16384) ? WT1 : WT2;
        int j = idx & 16383;
        int nn = j & 127, k = j >> 7;
        WT[nn * NF + k] = __float2half(W[k * NF + nn]);   // WT[n][k] = W[k][n]
    }
}

// ---------------- count: 4 edges/thread (dst guaranteed in [0,N)) ----------------
__global__ __launch_bounds__(256) void count_k(const int* __restrict__ dst,
                                               int* __restrict__ cnt, int E) {
    int e = (blockIdx.x * 256 + threadIdx.x) * 4;
    if (e + 3 < E) {
        int4 d = *(const int4*)(dst + e);
        atomicAdd(&cnt[d.x], 1); atomicAdd(&cnt[d.y], 1);
        atomicAdd(&cnt[d.z], 1); atomicAdd(&cnt[d.w], 1);
    } else {
        for (int k = e; k < E; k++) atomicAdd(&cnt[dst[k]], 1);
    }
}

// Phase 1: per-256-chunk local exclusive scan (into rowptr) + block totals + dinv.
__global__ __launch_bounds__(256) void pscan_local(
    const int* __restrict__ cnt, float* __restrict__ dinv,
    int* __restrict__ rowptr, int* __restrict__ blocksum, int n)
{
    __shared__ int sm[256];
    int tid = threadIdx.x;
    int i = blockIdx.x * 256 + tid;
    int v = (i < n) ? cnt[i] : 0;
    if (i < n) dinv[i] = rsqrtf((float)v + 1.0f);  // +1 = self-loop
    sm[tid] = v;
    __syncthreads();
    #pragma unroll
    for (int d = 1; d < 256; d <<= 1) {
        int t = (tid >= d) ? sm[tid - d] : 0;
        __syncthreads();
        sm[tid] += t;
        __syncthreads();
    }
    if (i < n) rowptr[i] = sm[tid] - v;            // local exclusive prefix
    if (tid == 255) blocksum[blockIdx.x] = sm[255];
}

// Phase 2+3 fused: each block reduces blocksum[0..blockIdx) itself (nb<=256),
// adds the offset, inits the fill cursor and rowptr[n].
__global__ __launch_bounds__(256) void add_off2(
    int* __restrict__ rowptr, int* __restrict__ cur,
    const int* __restrict__ blocksum, int n, int E, int nb)
{
    __shared__ int sm[256];
    int tid = threadIdx.x;
    sm[tid] = (tid < nb && tid < (int)blockIdx.x) ? blocksum[tid] : 0;
    __syncthreads();
    #pragma unroll
    for (int d = 128; d > 0; d >>= 1) {
        if (tid < d) sm[tid] += sm[tid + d];
        __syncthreads();
    }
    int offv = sm[0];   // exclusive prefix of block sums
    int i = blockIdx.x * 256 + tid;
    if (i < n) {
        int r = rowptr[i] + offv;
        rowptr[i] = r;
        cur[i] = r;
    }
    if (blockIdx.x == 0 && tid == 0) rowptr[n] = E;
}

// ---------------- fill: single pass, no partition, NT csr stores -----------------
// R2's write explosion (53MB for a 3.2MB array) was 8 XCD-L2s holding dirty
// copies of every csr line. NT stores stream past L2 -> single copy at LLC.
// One pass over edges (R9's 8x read amplification gone). Atomic cursor traffic
// (~26MB LLC RMW) is the remaining floor.
__global__ __launch_bounds__(256) void fill_k(
    const int* __restrict__ src, const int* __restrict__ dst,
    int* __restrict__ cur, int* __restrict__ csr, int E)
{
    int e = (blockIdx.x * 256 + threadIdx.x) * 4;
    if (e + 3 < E) {
        int4 d = *(const int4*)(dst + e);
        int4 s = *(const int4*)(src + e);
        int p0 = atomicAdd(&cur[d.x], 1);
        int p1 = atomicAdd(&cur[d.y], 1);
        int p2 = atomicAdd(&cur[d.z], 1);
        int p3 = atomicAdd(&cur[d.w], 1);
        __builtin_nontemporal_store(s.x, &csr[p0]);
        __builtin_nontemporal_store(s.y, &csr[p1]);
        __builtin_nontemporal_store(s.z, &csr[p2]);
        __builtin_nontemporal_store(s.w, &csr[p3]);
    } else {
        for (int k = e; k < E; k++) {
            int p = atomicAdd(&cur[dst[k]], 1);
            __builtin_nontemporal_store(src[k], &csr[p]);
        }
    }
}

// ---------------- MFMA GEMM (R8 LDS form — proven) -------------------------------
// out[i][j] = half( dinv[i] * sum_k X[i][k] W[k][j] )
// mfma_f32_16x16x32_f16: A[m=lane&15][k=quad*8+j]; B[k=quad*8+j][n=lane&15];
// D: row=quad*4+reg, col=lane&15. wlds pitch 136: 16B-aligned, <=2-way banks.

template<bool F32IN>
__device__ __forceinline__ void gemm_body(
    const void* __restrict__ Xv, const __half* __restrict__ WT,
    const float* __restrict__ dinv, __half* __restrict__ out, int M, int bid)
{
    __shared__ __half wlds[128][136];
    const int tid = threadIdx.x;

    {   // stage WT (128x128 halves): 2 threads/row, 64 halves (8 x half8) each
        int r = tid >> 1;
        int c0 = (tid & 1) * 64;
        const half8* s = (const half8*)(WT + (size_t)r * NF + c0);
        half8* d = (half8*)&wlds[r][c0];
        #pragma unroll
        for (int j = 0; j < 8; j++) d[j] = s[j];
    }
    __syncthreads();

    const int wave = tid >> 6, lane = tid & 63;
    const int quad = lane >> 4, l15 = lane & 15;
    const int rowA = bid * 64 + wave * 16 + l15;
    const int rowc = (rowA < M) ? rowA : (M - 1);   // clamp (dup row, never stored)

    half8 afr[4];
    if (F32IN) {
        const float* X = (const float*)Xv;
        #pragma unroll
        for (int kc = 0; kc < 4; kc++) {
            const floatx4* p = (const floatx4*)(X + (size_t)rowc * NF + kc * 32 + quad * 8);
            floatx4 u = p[0], v = p[1];
            half8 a;
            a[0] = (_Float16)u[0]; a[1] = (_Float16)u[1];
            a[2] = (_Float16)u[2]; a[3] = (_Float16)u[3];
            a[4] = (_Float16)v[0]; a[5] = (_Float16)v[1];
            a[6] = (_Float16)v[2]; a[7] = (_Float16)v[3];
            afr[kc] = a;
        }
    } else {
        const __half* X = (const __half*)Xv;
        #pragma unroll
        for (int kc = 0; kc < 4; kc++)
            afr[kc] = *(const half8*)(X + (size_t)rowc * NF + kc * 32 + quad * 8);
    }

    floatx4 acc[8];
    #pragma unroll
    for (int ct = 0; ct < 8; ct++) { floatx4 z = {0.f, 0.f, 0.f, 0.f}; acc[ct] = z; }

    #pragma unroll
    for (int kc = 0; kc < 4; kc++) {
        #pragma unroll
        for (int ct = 0; ct < 8; ct++) {
            half8 b = *(const half8*)&wlds[ct * 16 + l15][kc * 32 + quad * 8];
            acc[ct] = __builtin_amdgcn_mfma_f32_16x16x32_f16(afr[kc], b, acc[ct], 0, 0, 0);
        }
    }

    const int orow0 = bid * 64 + wave * 16 + quad * 4;
    #pragma unroll
    for (int r = 0; r < 4; r++) {
        int orow = orow0 + r;
        if (orow < M) {
            float s = dinv[orow];
            #pragma unroll
            for (int ct = 0; ct < 8; ct++)
                out[(size_t)orow * NF + ct * 16 + l15] = __float2half(acc[ct][r] * s);
        }
    }
}

__global__ __launch_bounds__(256) void gemm1_k(
    const float* __restrict__ X, const __half* __restrict__ WT,
    const float* __restrict__ dinv, __half* __restrict__ H, int M)
{
    gemm_body<true>(X, WT, dinv, H, M, blockIdx.x);
}

__global__ __launch_bounds__(256) void gemm2_k(
    const __half* __restrict__ A, const __half* __restrict__ WT,
    const float* __restrict__ dinv, __half* __restrict__ H, int M)
{
    gemm_body<false>(A, WT, dinv, H, M, blockIdx.x);
}

// ---------------- Aggregation: one wave per node, fp16 gather, fp32 accumulate --
// acc = hs[node] + sum_in hs[src]; res = dinv[node]*acc + bias.
// outh: half(relu(res)) (layer 1); else float res. 16 gathers in flight.

__global__ __launch_bounds__(256) void agg_k(
    const __half2* __restrict__ hs, const int* __restrict__ rowptr,
    const int* __restrict__ csr, const float* __restrict__ dinv,
    const float* __restrict__ bias, __half2* __restrict__ outh,
    float* __restrict__ outf, int n)
{
    int wave = threadIdx.x >> 6;
    int lane = threadIdx.x & 63;
    int node = blockIdx.x * 4 + wave;
    if (node >= n) return;

    const int HS = NF / 2;   // 64 half2 per row
    float2 acc = __half22float2(hs[(size_t)node * HS + lane]);  // self-loop

    int base = rowptr[node];
    int cnt  = rowptr[node + 1] - base;

    for (int off = 0; off < cnt; off += 64) {
        int m = min(64, cnt - off);
        int idx = 0;
        if (lane < m) idx = __builtin_nontemporal_load(&csr[base + off + lane]);
        int j = 0;
        for (; j + 15 < m; j += 16) {   // 16 gathers in flight
            int s[16];
            __half2 v[16];
            #pragma unroll
            for (int t = 0; t < 16; t++) s[t] = __shfl(idx, j + t, 64);
            #pragma unroll
            for (int t = 0; t < 16; t++) v[t] = hs[(size_t)s[t] * HS + lane];
            #pragma unroll
            for (int t = 0; t < 16; t++) {
                float2 f = __half22float2(v[t]);
                acc.x += f.x; acc.y += f.y;
            }
        }
        for (; j + 3 < m; j += 4) {     // 4-deep remainder
            int s0 = __shfl(idx, j, 64);
            int s1 = __shfl(idx, j + 1, 64);
            int s2 = __shfl(idx, j + 2, 64);
            int s3 = __shfl(idx, j + 3, 64);
            __half2 v0 = hs[(size_t)s0 * HS + lane];
            __half2 v1 = hs[(size_t)s1 * HS + lane];
            __half2 v2 = hs[(size_t)s2 * HS + lane];
            __half2 v3 = hs[(size_t)s3 * HS + lane];
            float2 f0 = __half22float2(v0), f1 = __half22float2(v1);
            float2 f2 = __half22float2(v2), f3 = __half22float2(v3);
            acc.x += (f0.x + f1.x) + (f2.x + f3.x);
            acc.y += (f0.y + f1.y) + (f2.y + f3.y);
        }
        for (; j < m; j++) {
            int s0 = __shfl(idx, j, 64);
            float2 f0 = __half22float2(hs[(size_t)s0 * HS + lane]);
            acc.x += f0.x; acc.y += f0.y;
        }
    }

    float s = dinv[node];
    float ox = s * acc.x + bias[2 * lane];
    float oy = s * acc.y + bias[2 * lane + 1];
    if (outh) {
        ox = fmaxf(ox, 0.f); oy = fmaxf(oy, 0.f);
        outh[(size_t)node * HS + lane] = __floats2half2_rn(ox, oy);
    } else {
        ((float2*)(outf + (size_t)node * NF))[lane] = make_float2(ox, oy);
    }
}

// ---------------- launch ----------------

extern "C" void kernel_launch(void* const* d_in, const int* in_sizes, int n_in,
                              void* d_out, int out_size, void* d_ws, size_t ws_size,
                              hipStream_t stream) {
    const float* x  = (const float*)d_in[0];
    const int*   ei = (const int*)d_in[1];
    const float* W1 = (const float*)d_in[2];
    const float* b1 = (const float*)d_in[3];
    const float* W2 = (const float*)d_in[4];
    const float* b2 = (const float*)d_in[5];
    float* out = (float*)d_out;

    const int N = in_sizes[0] / NF;   // 50000
    const int E = in_sizes[1] / 2;    // 800000
    const int* src = ei;
    const int* dst = ei + E;

    char* ws = (char*)d_ws;
    size_t off = 0;
    auto alloc = [&](size_t bytes) {
        void* p = ws + off;
        off += bytes;
        off = (off + 63) & ~(size_t)63;
        return p;
    };
    int*    cnt    = (int*)alloc((size_t)N * 4);        // reused as fill cursor
    int*    rowptr = (int*)alloc((size_t)(N + 1) * 4);
    int*    csr    = (int*)alloc((size_t)E * 4);
    float*  dinv   = (float*)alloc((size_t)N * 4);
    int*    bsum   = (int*)alloc((size_t)256 * 4);
    __half* WT1    = (__half*)alloc((size_t)NF * NF * 2);
    __half* WT2    = (__half*)alloc((size_t)NF * NF * 2);
    __half* H16    = (__half*)alloc((size_t)N * NF * 2);
    __half* A16    = (__half*)alloc((size_t)N * NF * 2);

    int nb = (N + 255) / 256;     // 196 blocks (<= 256, required by add_off2)
    int cb = (E / 4 + 255) / 256; // 4 edges/thread
    int gb = (N + 63) / 64;
    int ab = (N + 3) / 4;

    prep_k<<<nb + 128, 256, 0, stream>>>(cnt, N, nb, W1, W2, WT1, WT2);
    count_k<<<cb, 256, 0, stream>>>(dst, cnt, E);
    pscan_local<<<nb, 256, 0, stream>>>(cnt, dinv, rowptr, bsum, N);
    add_off2<<<nb, 256, 0, stream>>>(rowptr, cnt, bsum, N, E, nb);
    fill_k<<<cb, 256, 0, stream>>>(src, dst, cnt, csr, E);
    gemm1_k<<<gb, 256, 0, stream>>>(x, WT1, dinv, H16, N);
    agg_k<<<ab, 256, 0, stream>>>((const __half2*)H16, rowptr, csr, dinv, b1,
                                  (__half2*)A16, nullptr, N);
    gemm2_k<<<gb, 256, 0, stream>>>(A16, WT2, dinv, H16, N);
    agg_k<<<ab, 256, 0, stream>>>((const __half2*)H16, rowptr, csr, dinv, b2,
                                  nullptr, out, N);
}

// Round 11
// 217.312 us; speedup vs baseline: 1.2279x; 1.2279x over previous
//
#include <hip/hip_runtime.h>
#include <hip/hip_fp16.h>

#define NF 128    // feature dim, fixed by the problem
#define NP 8192   // max nodes per partition (N/8 rounded up; N<=65536)
#define KC 32     // edge chunks

typedef _Float16 half8 __attribute__((ext_vector_type(8)));
typedef float    floatx4 __attribute__((ext_vector_type(4)));

// ---------------- prep: convert/transpose W1,W2 to fp16 --------------------------
__global__ __launch_bounds__(256) void prep_k(
    const float* __restrict__ W1, const float* __restrict__ W2,
    __half* __restrict__ WT1, __half* __restrict__ WT2)
{
    int idx = blockIdx.x * 256 + threadIdx.x;   // 0..32767
    const float* W = (idx < 16384) ? W1 : W2;
    __half* WT     = (idx < 16384) ? WT1 : WT2;
    int j = idx & 16383;
    int nn = j & 127, k = j >> 7;
    WT[nn * NF + k] = __float2half(W[k * NF + nn]);   // WT[n][k] = W[k][n]
}

// ---------------- count2: LDS histogram per (chunk, partition) -------------------
// Block b: partition p=b&7 (-> XCD p by round-robin), chunk c=b>>3.
// Zero global atomics: histogram in LDS, coalesced writeout to pcnt[c][bin].
__global__ __launch_bounds__(512) void count2_k(
    const int* __restrict__ dst, int* __restrict__ pcnt, int E, int N, int Ec)
{
    __shared__ int lcnt[NP];
    const int p = blockIdx.x & 7, c = blockIdx.x >> 3;
    const int Np = (N + 7) >> 3;
    const int lo = p * Np, hi = min(lo + Np, N);
    const int sz = hi - lo;
    for (int i = threadIdx.x; i < sz; i += 512) lcnt[i] = 0;
    __syncthreads();

    const int e0 = c * Ec, e1 = min(e0 + Ec, E);
    for (int e = e0 + (int)threadIdx.x * 4; e + 3 < e1; e += 512 * 4) {
        int4 d = *(const int4*)(dst + e);
        if (d.x >= lo && d.x < hi) atomicAdd(&lcnt[d.x - lo], 1);
        if (d.y >= lo && d.y < hi) atomicAdd(&lcnt[d.y - lo], 1);
        if (d.z >= lo && d.z < hi) atomicAdd(&lcnt[d.z - lo], 1);
        if (d.w >= lo && d.w < hi) atomicAdd(&lcnt[d.w - lo], 1);
    }
    int rem0 = e0 + ((e1 - e0) & ~3);
    for (int e = rem0 + (int)threadIdx.x; e < e1; e += 512) {
        int d = dst[e];
        if (d >= lo && d < hi) atomicAdd(&lcnt[d - lo], 1);
    }
    __syncthreads();
    for (int i = threadIdx.x; i < sz; i += 512)
        pcnt[(size_t)c * N + lo + i] = lcnt[i];
}

// ---------------- pscan2: per-bin chunk-prefix (in-place) + block scan + dinv ----
// For each bin: total deg = sum_c pcnt[c][bin]; pcnt[c][bin] <- exclusive prefix
// (becomes coff). Then 256-wide block scan into rowptr-local + blocksum, dinv.
__global__ __launch_bounds__(256) void pscan2_k(
    int* __restrict__ pcnt, float* __restrict__ dinv,
    int* __restrict__ rowptr, int* __restrict__ blocksum, int n, int N)
{
    __shared__ int sm[256];
    int tid = threadIdx.x;
    int bin = blockIdx.x * 256 + tid;
    int total = 0;
    if (bin < n) {
        #pragma unroll 4
        for (int c = 0; c < KC; c++) {
            size_t o = (size_t)c * N + bin;
            int v = pcnt[o];
            pcnt[o] = total;   // exclusive chunk prefix (coff)
            total += v;
        }
        dinv[bin] = rsqrtf((float)total + 1.0f);  // +1 = self-loop
    }
    sm[tid] = total;
    __syncthreads();
    #pragma unroll
    for (int d = 1; d < 256; d <<= 1) {
        int t = (tid >= d) ? sm[tid - d] : 0;
        __syncthreads();
        sm[tid] += t;
        __syncthreads();
    }
    if (bin < n) rowptr[bin] = sm[tid] - total;    // local exclusive prefix
    if (tid == 255) blocksum[blockIdx.x] = sm[255];
}

// ---------------- add_off2: block-offset add (nb<=256) + rowptr[n] ---------------
__global__ __launch_bounds__(256) void add_off2(
    int* __restrict__ rowptr, const int* __restrict__ blocksum, int n, int E, int nb)
{
    __shared__ int sm[256];
    int tid = threadIdx.x;
    sm[tid] = (tid < nb && tid < (int)blockIdx.x) ? blocksum[tid] : 0;
    __syncthreads();
    #pragma unroll
    for (int d = 128; d > 0; d >>= 1) {
        if (tid < d) sm[tid] += sm[tid + d];
        __syncthreads();
    }
    int offv = sm[0];
    int i = blockIdx.x * 256 + tid;
    if (i < n) rowptr[i] += offv;
    if (blockIdx.x == 0 && tid == 0) rowptr[n] = E;
}

// ---------------- fill2: LDS cursor, no global atomics ---------------------------
// Block (c,p): lcur[i] = rowptr[lo+i] + coff[c][lo+i]; scatter csr within the
// contiguous partition window (one XCD's L2 holds it -> single dirty copy).
__global__ __launch_bounds__(512) void fill2_k(
    const int* __restrict__ src, const int* __restrict__ dst,
    const int* __restrict__ rowptr, const int* __restrict__ coff,
    int* __restrict__ csr, int E, int N, int Ec)
{
    __shared__ int lcur[NP];
    const int p = blockIdx.x & 7, c = blockIdx.x >> 3;
    const int Np = (N + 7) >> 3;
    const int lo = p * Np, hi = min(lo + Np, N);
    const int sz = hi - lo;
    for (int i = threadIdx.x; i < sz; i += 512)
        lcur[i] = rowptr[lo + i] + coff[(size_t)c * N + lo + i];
    __syncthreads();

    const int e0 = c * Ec, e1 = min(e0 + Ec, E);
    for (int e = e0 + (int)threadIdx.x * 4; e + 3 < e1; e += 512 * 4) {
        int4 d = *(const int4*)(dst + e);
        int4 s = *(const int4*)(src + e);
        if (d.x >= lo && d.x < hi) csr[atomicAdd(&lcur[d.x - lo], 1)] = s.x;
        if (d.y >= lo && d.y < hi) csr[atomicAdd(&lcur[d.y - lo], 1)] = s.y;
        if (d.z >= lo && d.z < hi) csr[atomicAdd(&lcur[d.z - lo], 1)] = s.z;
        if (d.w >= lo && d.w < hi) csr[atomicAdd(&lcur[d.w - lo], 1)] = s.w;
    }
    int rem0 = e0 + ((e1 - e0) & ~3);
    for (int e = rem0 + (int)threadIdx.x; e < e1; e += 512) {
        int d = dst[e];
        if (d >= lo && d < hi) csr[atomicAdd(&lcur[d - lo], 1)] = src[e];
    }
}

// ---------------- MFMA GEMM (R8 LDS form — proven) -------------------------------
// out[i][j] = half( dinv[i] * sum_k X[i][k] W[k][j] )
// mfma_f32_16x16x32_f16: A[m=lane&15][k=quad*8+j]; B[k=quad*8+j][n=lane&15];
// D: row=quad*4+reg, col=lane&15. wlds pitch 136: 16B-aligned, <=2-way banks.

template<bool F32IN>
__device__ __forceinline__ void gemm_body(
    const void* __restrict__ Xv, const __half* __restrict__ WT,
    const float* __restrict__ dinv, __half* __restrict__ out, int M, int bid)
{
    __shared__ __half wlds[128][136];
    const int tid = threadIdx.x;

    {   // stage WT (128x128 halves): 2 threads/row, 64 halves (8 x half8) each
        int r = tid >> 1;
        int c0 = (tid & 1) * 64;
        const half8* s = (const half8*)(WT + (size_t)r * NF + c0);
        half8* d = (half8*)&wlds[r][c0];
        #pragma unroll
        for (int j = 0; j < 8; j++) d[j] = s[j];
    }
    __syncthreads();

    const int wave = tid >> 6, lane = tid & 63;
    const int quad = lane >> 4, l15 = lane & 15;
    const int rowA = bid * 64 + wave * 16 + l15;
    const int rowc = (rowA < M) ? rowA : (M - 1);   // clamp (dup row, never stored)

    half8 afr[4];
    if (F32IN) {
        const float* X = (const float*)Xv;
        #pragma unroll
        for (int kc = 0; kc < 4; kc++) {
            const floatx4* p = (const floatx4*)(X + (size_t)rowc * NF + kc * 32 + quad * 8);
            floatx4 u = p[0], v = p[1];
            half8 a;
            a[0] = (_Float16)u[0]; a[1] = (_Float16)u[1];
            a[2] = (_Float16)u[2]; a[3] = (_Float16)u[3];
            a[4] = (_Float16)v[0]; a[5] = (_Float16)v[1];
            a[6] = (_Float16)v[2]; a[7] = (_Float16)v[3];
            afr[kc] = a;
        }
    } else {
        const __half* X = (const __half*)Xv;
        #pragma unroll
        for (int kc = 0; kc < 4; kc++)
            afr[kc] = *(const half8*)(X + (size_t)rowc * NF + kc * 32 + quad * 8);
    }

    floatx4 acc[8];
    #pragma unroll
    for (int ct = 0; ct < 8; ct++) { floatx4 z = {0.f, 0.f, 0.f, 0.f}; acc[ct] = z; }

    #pragma unroll
    for (int kc = 0; kc < 4; kc++) {
        #pragma unroll
        for (int ct = 0; ct < 8; ct++) {
            half8 b = *(const half8*)&wlds[ct * 16 + l15][kc * 32 + quad * 8];
            acc[ct] = __builtin_amdgcn_mfma_f32_16x16x32_f16(afr[kc], b, acc[ct], 0, 0, 0);
        }
    }

    const int orow0 = bid * 64 + wave * 16 + quad * 4;
    #pragma unroll
    for (int r = 0; r < 4; r++) {
        int orow = orow0 + r;
        if (orow < M) {
            float s = dinv[orow];
            #pragma unroll
            for (int ct = 0; ct < 8; ct++)
                out[(size_t)orow * NF + ct * 16 + l15] = __float2half(acc[ct][r] * s);
        }
    }
}

__global__ __launch_bounds__(256) void gemm1_k(
    const float* __restrict__ X, const __half* __restrict__ WT,
    const float* __restrict__ dinv, __half* __restrict__ H, int M)
{
    gemm_body<true>(X, WT, dinv, H, M, blockIdx.x);
}

__global__ __launch_bounds__(256) void gemm2_k(
    const __half* __restrict__ A, const __half* __restrict__ WT,
    const float* __restrict__ dinv, __half* __restrict__ H, int M)
{
    gemm_body<false>(A, WT, dinv, H, M, blockIdx.x);
}

// ---------------- Aggregation: one wave per node, fp16 gather, fp32 accumulate --
// acc = hs[node] + sum_in hs[src]; res = dinv[node]*acc + bias.
// outh: half(relu(res)) (layer 1); else float res. 16 gathers in flight.

__global__ __launch_bounds__(256) void agg_k(
    const __half2* __restrict__ hs, const int* __restrict__ rowptr,
    const int* __restrict__ csr, const float* __restrict__ dinv,
    const float* __restrict__ bias, __half2* __restrict__ outh,
    float* __restrict__ outf, int n)
{
    int wave = threadIdx.x >> 6;
    int lane = threadIdx.x & 63;
    int node = blockIdx.x * 4 + wave;
    if (node >= n) return;

    const int HS = NF / 2;   // 64 half2 per row
    float2 acc = __half22float2(hs[(size_t)node * HS + lane]);  // self-loop

    int base = rowptr[node];
    int cnt  = rowptr[node + 1] - base;

    for (int off = 0; off < cnt; off += 64) {
        int m = min(64, cnt - off);
        int idx = 0;
        if (lane < m) idx = __builtin_nontemporal_load(&csr[base + off + lane]);
        int j = 0;
        for (; j + 15 < m; j += 16) {   // 16 gathers in flight
            int s[16];
            __half2 v[16];
            #pragma unroll
            for (int t = 0; t < 16; t++) s[t] = __shfl(idx, j + t, 64);
            #pragma unroll
            for (int t = 0; t < 16; t++) v[t] = hs[(size_t)s[t] * HS + lane];
            #pragma unroll
            for (int t = 0; t < 16; t++) {
                float2 f = __half22float2(v[t]);
                acc.x += f.x; acc.y += f.y;
            }
        }
        for (; j + 3 < m; j += 4) {     // 4-deep remainder
            int s0 = __shfl(idx, j, 64);
            int s1 = __shfl(idx, j + 1, 64);
            int s2 = __shfl(idx, j + 2, 64);
            int s3 = __shfl(idx, j + 3, 64);
            __half2 v0 = hs[(size_t)s0 * HS + lane];
            __half2 v1 = hs[(size_t)s1 * HS + lane];
            __half2 v2 = hs[(size_t)s2 * HS + lane];
            __half2 v3 = hs[(size_t)s3 * HS + lane];
            float2 f0 = __half22float2(v0), f1 = __half22float2(v1);
            float2 f2 = __half22float2(v2), f3 = __half22float2(v3);
            acc.x += (f0.x + f1.x) + (f2.x + f3.x);
            acc.y += (f0.y + f1.y) + (f2.y + f3.y);
        }
        for (; j < m; j++) {
            int s0 = __shfl(idx, j, 64);
            float2 f0 = __half22float2(hs[(size_t)s0 * HS + lane]);
            acc.x += f0.x; acc.y += f0.y;
        }
    }

    float s = dinv[node];
    float ox = s * acc.x + bias[2 * lane];
    float oy = s * acc.y + bias[2 * lane + 1];
    if (outh) {
        ox = fmaxf(ox, 0.f); oy = fmaxf(oy, 0.f);
        outh[(size_t)node * HS + lane] = __floats2half2_rn(ox, oy);
    } else {
        ((float2*)(outf + (size_t)node * NF))[lane] = make_float2(ox, oy);
    }
}

// ---------------- launch ----------------

extern "C" void kernel_launch(void* const* d_in, const int* in_sizes, int n_in,
                              void* d_out, int out_size, void* d_ws, size_t ws_size,
                              hipStream_t stream) {
    const float* x  = (const float*)d_in[0];
    const int*   ei = (const int*)d_in[1];
    const float* W1 = (const float*)d_in[2];
    const float* b1 = (const float*)d_in[3];
    const float* W2 = (const float*)d_in[4];
    const float* b2 = (const float*)d_in[5];
    float* out = (float*)d_out;

    const int N = in_sizes[0] / NF;   // 50000
    const int E = in_sizes[1] / 2;    // 800000
    const int* src = ei;
    const int* dst = ei + E;

    char* ws = (char*)d_ws;
    size_t off = 0;
    auto alloc = [&](size_t bytes) {
        void* p = ws + off;
        off += bytes;
        off = (off + 63) & ~(size_t)63;
        return p;
    };
    int*    pcnt   = (int*)alloc((size_t)KC * N * 4);   // per-chunk counts -> coff
    int*    rowptr = (int*)alloc((size_t)(N + 1) * 4);
    int*    csr    = (int*)alloc((size_t)E * 4);
    float*  dinv   = (float*)alloc((size_t)N * 4);
    int*    bsum   = (int*)alloc((size_t)256 * 4);
    __half* WT1    = (__half*)alloc((size_t)NF * NF * 2);
    __half* WT2    = (__half*)alloc((size_t)NF * NF * 2);
    __half* H16    = (__half*)alloc((size_t)N * NF * 2);
    __half* A16    = (__half*)alloc((size_t)N * NF * 2);

    int nb = (N + 255) / 256;                 // 196 (<=256, required by add_off2)
    int Ec = (((E + KC - 1) / KC) + 3) & ~3;  // chunk size, multiple of 4
    int gb = (N + 63) / 64;
    int ab = (N + 3) / 4;

    prep_k<<<128, 256, 0, stream>>>(W1, W2, WT1, WT2);
    count2_k<<<KC * 8, 512, 0, stream>>>(dst, pcnt, E, N, Ec);
    pscan2_k<<<nb, 256, 0, stream>>>(pcnt, dinv, rowptr, bsum, N, N);
    add_off2<<<nb, 256, 0, stream>>>(rowptr, bsum, N, E, nb);
    fill2_k<<<KC * 8, 512, 0, stream>>>(src, dst, rowptr, pcnt, csr, E, N, Ec);
    gemm1_k<<<gb, 256, 0, stream>>>(x, WT1, dinv, H16, N);
    agg_k<<<ab, 256, 0, stream>>>((const __half2*)H16, rowptr, csr, dinv, b1,
                                  (__half2*)A16, nullptr, N);
    gemm2_k<<<gb, 256, 0, stream>>>(A16, WT2, dinv, H16, N);
    agg_k<<<ab, 256, 0, stream>>>((const __half2*)H16, rowptr, csr, dinv, b2,
                                  nullptr, out, N);
}

// Round 12
// 216.280 us; speedup vs baseline: 1.2338x; 1.0048x over previous
//
#include <hip/hip_runtime.h>
#include <hip/hip_fp16.h>

#define NF 128    // feature dim, fixed by the problem
#define KC 64     // edge chunks
#define NPART 4   // node partitions (N/4 ints must fit LDS: 12500*4B = 50KB)

typedef _Float16 half8 __attribute__((ext_vector_type(8)));
typedef float    floatx4 __attribute__((ext_vector_type(4)));

// ---------------- count2: LDS histogram per (chunk, partition) -------------------
// Block b: partition p=b&3, chunk c=b>>2. Zero global atomics: histogram in
// LDS, coalesced writeout to pcnt[c][bin]. P=4 (vs 8) halves edge re-visits.
__global__ __launch_bounds__(512) void count2_k(
    const int* __restrict__ dst, int* __restrict__ pcnt, int E, int N, int Ec)
{
    __shared__ int lcnt[12544];
    const int p = blockIdx.x & 3, c = blockIdx.x >> 2;
    const int Np = (N + 3) >> 2;
    const int lo = p * Np, hi = min(lo + Np, N);
    const int sz = hi - lo;
    for (int i = threadIdx.x; i < sz; i += 512) lcnt[i] = 0;
    __syncthreads();

    const int e0 = c * Ec, e1 = min(e0 + Ec, E);
    for (int e = e0 + (int)threadIdx.x * 4; e + 3 < e1; e += 512 * 4) {
        int4 d = *(const int4*)(dst + e);
        if (d.x >= lo && d.x < hi) atomicAdd(&lcnt[d.x - lo], 1);
        if (d.y >= lo && d.y < hi) atomicAdd(&lcnt[d.y - lo], 1);
        if (d.z >= lo && d.z < hi) atomicAdd(&lcnt[d.z - lo], 1);
        if (d.w >= lo && d.w < hi) atomicAdd(&lcnt[d.w - lo], 1);
    }
    int rem0 = e0 + ((e1 - e0) & ~3);
    for (int e = rem0 + (int)threadIdx.x; e < e1; e += 512) {
        int d = dst[e];
        if (d >= lo && d < hi) atomicAdd(&lcnt[d - lo], 1);
    }
    __syncthreads();
    for (int i = threadIdx.x; i < sz; i += 512)
        pcnt[(size_t)c * N + lo + i] = lcnt[i];
}

// ---------------- pscan2 (+fused W-transpose) ------------------------------------
// Blocks < nb: per-bin chunk-prefix over KC chunks (pcnt in-place -> coff),
// dinv, 256-wide local scan into rowptr + blocksum.
// Blocks >= nb: convert/transpose W1,W2 to fp16 WT[n][k]=W[k][n] (prep fused).
__global__ __launch_bounds__(256) void pscan2_k(
    int* __restrict__ pcnt, float* __restrict__ dinv,
    int* __restrict__ rowptr, int* __restrict__ blocksum, int n, int N, int nb,
    const float* __restrict__ W1, const float* __restrict__ W2,
    __half* __restrict__ WT1, __half* __restrict__ WT2)
{
    if ((int)blockIdx.x >= nb) {
        int idx = ((int)blockIdx.x - nb) * 256 + threadIdx.x;   // 0..32767
        const float* W = (idx < 16384) ? W1 : W2;
        __half* WT     = (idx < 16384) ? WT1 : WT2;
        int j = idx & 16383;
        int nn = j & 127, k = j >> 7;
        WT[nn * NF + k] = __float2half(W[k * NF + nn]);
        return;
    }
    __shared__ int sm[256];
    int tid = threadIdx.x;
    int bin = blockIdx.x * 256 + tid;
    int total = 0;
    if (bin < n) {
        #pragma unroll 4
        for (int c = 0; c < KC; c++) {
            size_t o = (size_t)c * N + bin;
            int v = pcnt[o];
            pcnt[o] = total;   // exclusive chunk prefix (coff)
            total += v;
        }
        dinv[bin] = rsqrtf((float)total + 1.0f);  // +1 = self-loop
    }
    sm[tid] = total;
    __syncthreads();
    #pragma unroll
    for (int d = 1; d < 256; d <<= 1) {
        int t = (tid >= d) ? sm[tid - d] : 0;
        __syncthreads();
        sm[tid] += t;
        __syncthreads();
    }
    if (bin < n) rowptr[bin] = sm[tid] - total;    // local exclusive prefix
    if (tid == 255) blocksum[blockIdx.x] = sm[255];
}

// ---------------- add_off2: block-offset add (nb<=256) + rowptr[n] ---------------
__global__ __launch_bounds__(256) void add_off2(
    int* __restrict__ rowptr, const int* __restrict__ blocksum, int n, int E, int nb)
{
    __shared__ int sm[256];
    int tid = threadIdx.x;
    sm[tid] = (tid < nb && tid < (int)blockIdx.x) ? blocksum[tid] : 0;
    __syncthreads();
    #pragma unroll
    for (int d = 128; d > 0; d >>= 1) {
        if (tid < d) sm[tid] += sm[tid + d];
        __syncthreads();
    }
    int offv = sm[0];
    int i = blockIdx.x * 256 + tid;
    if (i < n) rowptr[i] += offv;
    if (blockIdx.x == 0 && tid == 0) rowptr[n] = E;
}

// ---------------- fill2: LDS cursor, no global atomics ---------------------------
// Block (c,p): lcur[i] = rowptr[lo+i] + coff[c][lo+i]; scatter csr within the
// contiguous partition window (<=2 XCD L2 copies at P=4).
__global__ __launch_bounds__(512) void fill2_k(
    const int* __restrict__ src, const int* __restrict__ dst,
    const int* __restrict__ rowptr, const int* __restrict__ coff,
    int* __restrict__ csr, int E, int N, int Ec)
{
    __shared__ int lcur[12544];
    const int p = blockIdx.x & 3, c = blockIdx.x >> 2;
    const int Np = (N + 3) >> 2;
    const int lo = p * Np, hi = min(lo + Np, N);
    const int sz = hi - lo;
    for (int i = threadIdx.x; i < sz; i += 512)
        lcur[i] = rowptr[lo + i] + coff[(size_t)c * N + lo + i];
    __syncthreads();

    const int e0 = c * Ec, e1 = min(e0 + Ec, E);
    for (int e = e0 + (int)threadIdx.x * 4; e + 3 < e1; e += 512 * 4) {
        int4 d = *(const int4*)(dst + e);
        int4 s = *(const int4*)(src + e);
        if (d.x >= lo && d.x < hi) csr[atomicAdd(&lcur[d.x - lo], 1)] = s.x;
        if (d.y >= lo && d.y < hi) csr[atomicAdd(&lcur[d.y - lo], 1)] = s.y;
        if (d.z >= lo && d.z < hi) csr[atomicAdd(&lcur[d.z - lo], 1)] = s.z;
        if (d.w >= lo && d.w < hi) csr[atomicAdd(&lcur[d.w - lo], 1)] = s.w;
    }
    int rem0 = e0 + ((e1 - e0) & ~3);
    for (int e = rem0 + (int)threadIdx.x; e < e1; e += 512) {
        int d = dst[e];
        if (d >= lo && d < hi) csr[atomicAdd(&lcur[d - lo], 1)] = src[e];
    }
}

// ---------------- MFMA GEMM (R8 LDS form — proven) -------------------------------
// out[i][j] = half( dinv[i] * sum_k X[i][k] W[k][j] )
// mfma_f32_16x16x32_f16: A[m=lane&15][k=quad*8+j]; B[k=quad*8+j][n=lane&15];
// D: row=quad*4+reg, col=lane&15. wlds pitch 136: 16B-aligned, <=2-way banks.

template<bool F32IN>
__device__ __forceinline__ void gemm_body(
    const void* __restrict__ Xv, const __half* __restrict__ WT,
    const float* __restrict__ dinv, __half* __restrict__ out, int M, int bid)
{
    __shared__ __half wlds[128][136];
    const int tid = threadIdx.x;

    {   // stage WT (128x128 halves): 2 threads/row, 64 halves (8 x half8) each
        int r = tid >> 1;
        int c0 = (tid & 1) * 64;
        const half8* s = (const half8*)(WT + (size_t)r * NF + c0);
        half8* d = (half8*)&wlds[r][c0];
        #pragma unroll
        for (int j = 0; j < 8; j++) d[j] = s[j];
    }
    __syncthreads();

    const int wave = tid >> 6, lane = tid & 63;
    const int quad = lane >> 4, l15 = lane & 15;
    const int rowA = bid * 64 + wave * 16 + l15;
    const int rowc = (rowA < M) ? rowA : (M - 1);   // clamp (dup row, never stored)

    half8 afr[4];
    if (F32IN) {
        const float* X = (const float*)Xv;
        #pragma unroll
        for (int kc = 0; kc < 4; kc++) {
            const floatx4* p = (const floatx4*)(X + (size_t)rowc * NF + kc * 32 + quad * 8);
            floatx4 u = p[0], v = p[1];
            half8 a;
            a[0] = (_Float16)u[0]; a[1] = (_Float16)u[1];
            a[2] = (_Float16)u[2]; a[3] = (_Float16)u[3];
            a[4] = (_Float16)v[0]; a[5] = (_Float16)v[1];
            a[6] = (_Float16)v[2]; a[7] = (_Float16)v[3];
            afr[kc] = a;
        }
    } else {
        const __half* X = (const __half*)Xv;
        #pragma unroll
        for (int kc = 0; kc < 4; kc++)
            afr[kc] = *(const half8*)(X + (size_t)rowc * NF + kc * 32 + quad * 8);
    }

    floatx4 acc[8];
    #pragma unroll
    for (int ct = 0; ct < 8; ct++) { floatx4 z = {0.f, 0.f, 0.f, 0.f}; acc[ct] = z; }

    #pragma unroll
    for (int kc = 0; kc < 4; kc++) {
        #pragma unroll
        for (int ct = 0; ct < 8; ct++) {
            half8 b = *(const half8*)&wlds[ct * 16 + l15][kc * 32 + quad * 8];
            acc[ct] = __builtin_amdgcn_mfma_f32_16x16x32_f16(afr[kc], b, acc[ct], 0, 0, 0);
        }
    }

    const int orow0 = bid * 64 + wave * 16 + quad * 4;
    #pragma unroll
    for (int r = 0; r < 4; r++) {
        int orow = orow0 + r;
        if (orow < M) {
            float s = dinv[orow];
            #pragma unroll
            for (int ct = 0; ct < 8; ct++)
                out[(size_t)orow * NF + ct * 16 + l15] = __float2half(acc[ct][r] * s);
        }
    }
}

__global__ __launch_bounds__(256) void gemm1_k(
    const float* __restrict__ X, const __half* __restrict__ WT,
    const float* __restrict__ dinv, __half* __restrict__ H, int M)
{
    gemm_body<true>(X, WT, dinv, H, M, blockIdx.x);
}

__global__ __launch_bounds__(256) void gemm2_k(
    const __half* __restrict__ A, const __half* __restrict__ WT,
    const float* __restrict__ dinv, __half* __restrict__ H, int M)
{
    gemm_body<false>(A, WT, dinv, H, M, blockIdx.x);
}

// ---------------- Aggregation: one wave per node, fp16 gather, fp32 accumulate --
// acc = hs[node] + sum_in hs[src]; res = dinv[node]*acc + bias.
// outh: half(relu(res)) (layer 1); else float res.
// 16-deep main loop; tail uses clamped+predicated 8-groups so every node keeps
// >=8 gathers in flight (Poisson(16) degrees: old 4-deep/scalar tail dominated).

__global__ __launch_bounds__(256) void agg_k(
    const __half2* __restrict__ hs, const int* __restrict__ rowptr,
    const int* __restrict__ csr, const float* __restrict__ dinv,
    const float* __restrict__ bias, __half2* __restrict__ outh,
    float* __restrict__ outf, int n)
{
    int wave = threadIdx.x >> 6;
    int lane = threadIdx.x & 63;
    int node = blockIdx.x * 4 + wave;
    if (node >= n) return;

    const int HS = NF / 2;   // 64 half2 per row
    float2 acc = __half22float2(hs[(size_t)node * HS + lane]);  // self-loop

    int base = rowptr[node];
    int cnt  = rowptr[node + 1] - base;

    for (int off = 0; off < cnt; off += 64) {
        int m = min(64, cnt - off);
        int idx = 0;
        if (lane < m) idx = __builtin_nontemporal_load(&csr[base + off + lane]);
        int j = 0;
        for (; j + 15 < m; j += 16) {   // 16 gathers in flight
            int s[16];
            __half2 v[16];
            #pragma unroll
            for (int t = 0; t < 16; t++) s[t] = __shfl(idx, j + t, 64);
            #pragma unroll
            for (int t = 0; t < 16; t++) v[t] = hs[(size_t)s[t] * HS + lane];
            #pragma unroll
            for (int t = 0; t < 16; t++) {
                float2 f = __half22float2(v[t]);
                acc.x += f.x; acc.y += f.y;
            }
        }
        for (; j < m; j += 8) {         // clamped 8-group tail (dup last edge)
            int s[8];
            __half2 v[8];
            #pragma unroll
            for (int t = 0; t < 8; t++) s[t] = __shfl(idx, min(j + t, m - 1), 64);
            #pragma unroll
            for (int t = 0; t < 8; t++) v[t] = hs[(size_t)s[t] * HS + lane];
            #pragma unroll
            for (int t = 0; t < 8; t++) {
                if (j + t < m) {
                    float2 f = __half22float2(v[t]);
                    acc.x += f.x; acc.y += f.y;
                }
            }
        }
    }

    float s = dinv[node];
    float ox = s * acc.x + bias[2 * lane];
    float oy = s * acc.y + bias[2 * lane + 1];
    if (outh) {
        ox = fmaxf(ox, 0.f); oy = fmaxf(oy, 0.f);
        outh[(size_t)node * HS + lane] = __floats2half2_rn(ox, oy);
    } else {
        ((float2*)(outf + (size_t)node * NF))[lane] = make_float2(ox, oy);
    }
}

// ---------------- launch ----------------

extern "C" void kernel_launch(void* const* d_in, const int* in_sizes, int n_in,
                              void* d_out, int out_size, void* d_ws, size_t ws_size,
                              hipStream_t stream) {
    const float* x  = (const float*)d_in[0];
    const int*   ei = (const int*)d_in[1];
    const float* W1 = (const float*)d_in[2];
    const float* b1 = (const float*)d_in[3];
    const float* W2 = (const float*)d_in[4];
    const float* b2 = (const float*)d_in[5];
    float* out = (float*)d_out;

    const int N = in_sizes[0] / NF;   // 50000
    const int E = in_sizes[1] / 2;    // 800000
    const int* src = ei;
    const int* dst = ei + E;

    char* ws = (char*)d_ws;
    size_t off = 0;
    auto alloc = [&](size_t bytes) {
        void* p = ws + off;
        off += bytes;
        off = (off + 63) & ~(size_t)63;
        return p;
    };
    int*    pcnt   = (int*)alloc((size_t)KC * N * 4);   // per-chunk counts -> coff
    int*    rowptr = (int*)alloc((size_t)(N + 1) * 4);
    int*    csr    = (int*)alloc((size_t)E * 4);
    float*  dinv   = (float*)alloc((size_t)N * 4);
    int*    bsum   = (int*)alloc((size_t)256 * 4);
    __half* WT1    = (__half*)alloc((size_t)NF * NF * 2);
    __half* WT2    = (__half*)alloc((size_t)NF * NF * 2);
    __half* H16    = (__half*)alloc((size_t)N * NF * 2);
    __half* A16    = (__half*)alloc((size_t)N * NF * 2);

    int nb = (N + 255) / 256;                 // 196 (<=256, required by add_off2)
    int Ec = (((E + KC - 1) / KC) + 3) & ~3;  // chunk size, multiple of 4
    int gb = (N + 63) / 64;
    int ab = (N + 3) / 4;

    count2_k<<<KC * NPART, 512, 0, stream>>>(dst, pcnt, E, N, Ec);
    pscan2_k<<<nb + 128, 256, 0, stream>>>(pcnt, dinv, rowptr, bsum, N, N, nb,
                                           W1, W2, WT1, WT2);
    add_off2<<<nb, 256, 0, stream>>>(rowptr, bsum, N, E, nb);
    fill2_k<<<KC * NPART, 512, 0, stream>>>(src, dst, rowptr, pcnt, csr, E, N, Ec);
    gemm1_k<<<gb, 256, 0, stream>>>(x, WT1, dinv, H16, N);
    agg_k<<<ab, 256, 0, stream>>>((const __half2*)H16, rowptr, csr, dinv, b1,
                                  (__half2*)A16, nullptr, N);
    gemm2_k<<<gb, 256, 0, stream>>>(A16, WT2, dinv, H16, N);
    agg_k<<<ab, 256, 0, stream>>>((const __half2*)H16, rowptr, csr, dinv, b2,
                                  nullptr, out, N);
}

// Round 13
// 210.336 us; speedup vs baseline: 1.2687x; 1.0283x over previous
//
#include <hip/hip_runtime.h>
#include <hip/hip_fp16.h>

#define NF 128    // feature dim, fixed by the problem
#define KC 64     // edge chunks
#define NPART 4   // node partitions (N/4 ints must fit LDS: 12500*4B = 50KB)
#define NPMAX 12544

typedef _Float16 half8 __attribute__((ext_vector_type(8)));
typedef _Float16 half4v __attribute__((ext_vector_type(4)));
typedef float    floatx4 __attribute__((ext_vector_type(4)));

// ---------------- count2: LDS histogram per (chunk, partition) -------------------
// Block b: partition p=b&3, chunk c=b>>2. Zero global atomics. pcnt is ushort
// (chunk-level counts <= ~60): halves the pcnt stream vs int.
__global__ __launch_bounds__(512) void count2_k(
    const int* __restrict__ dst, unsigned short* __restrict__ pcnt,
    int E, int N, int Ec)
{
    __shared__ int lcnt[NPMAX];
    const int p = blockIdx.x & 3, c = blockIdx.x >> 2;
    const int Np = (N + 3) >> 2;
    const int lo = p * Np, hi = min(lo + Np, N);
    const int sz = hi - lo;
    for (int i = threadIdx.x; i < sz; i += 512) lcnt[i] = 0;
    __syncthreads();

    const int e0 = c * Ec, e1 = min(e0 + Ec, E);
    for (int e = e0 + (int)threadIdx.x * 4; e + 3 < e1; e += 512 * 4) {
        int4 d = *(const int4*)(dst + e);
        if (d.x >= lo && d.x < hi) atomicAdd(&lcnt[d.x - lo], 1);
        if (d.y >= lo && d.y < hi) atomicAdd(&lcnt[d.y - lo], 1);
        if (d.z >= lo && d.z < hi) atomicAdd(&lcnt[d.z - lo], 1);
        if (d.w >= lo && d.w < hi) atomicAdd(&lcnt[d.w - lo], 1);
    }
    int rem0 = e0 + ((e1 - e0) & ~3);
    for (int e = rem0 + (int)threadIdx.x; e < e1; e += 512) {
        int d = dst[e];
        if (d >= lo && d < hi) atomicAdd(&lcnt[d - lo], 1);
    }
    __syncthreads();
    for (int i = threadIdx.x; i < sz; i += 512)
        pcnt[(size_t)c * N + lo + i] = (unsigned short)lcnt[i];
}

// ---------------- pscan2 (+fused W-transpose) ------------------------------------
// Blocks < nb: per-bin chunk-prefix over KC chunks (pcnt in-place -> coff),
// dinv, 256-wide local scan into rowptr + blocksum.
// Blocks >= nb: convert/transpose W1,W2 to fp16 WT[n][k]=W[k][n].
__global__ __launch_bounds__(256) void pscan2_k(
    unsigned short* __restrict__ pcnt, float* __restrict__ dinv,
    int* __restrict__ rowptr, int* __restrict__ blocksum, int n, int N, int nb,
    const float* __restrict__ W1, const float* __restrict__ W2,
    __half* __restrict__ WT1, __half* __restrict__ WT2)
{
    if ((int)blockIdx.x >= nb) {
        int idx = ((int)blockIdx.x - nb) * 256 + threadIdx.x;   // 0..32767
        const float* W = (idx < 16384) ? W1 : W2;
        __half* WT     = (idx < 16384) ? WT1 : WT2;
        int j = idx & 16383;
        int nn = j & 127, k = j >> 7;
        WT[nn * NF + k] = __float2half(W[k * NF + nn]);
        return;
    }
    __shared__ int sm[256];
    int tid = threadIdx.x;
    int bin = blockIdx.x * 256 + tid;
    int total = 0;
    if (bin < n) {
        #pragma unroll 4
        for (int c = 0; c < KC; c++) {
            size_t o = (size_t)c * N + bin;
            int v = pcnt[o];
            pcnt[o] = (unsigned short)total;   // exclusive chunk prefix (coff)
            total += v;
        }
        dinv[bin] = rsqrtf((float)total + 1.0f);  // +1 = self-loop
    }
    sm[tid] = total;
    __syncthreads();
    #pragma unroll
    for (int d = 1; d < 256; d <<= 1) {
        int t = (tid >= d) ? sm[tid - d] : 0;
        __syncthreads();
        sm[tid] += t;
        __syncthreads();
    }
    if (bin < n) rowptr[bin] = sm[tid] - total;    // local exclusive prefix
    if (tid == 255) blocksum[blockIdx.x] = sm[255];
}

// ---------------- MFMA GEMM body (512 threads, 128 rows/block) -------------------
// out[i][j] = half( dinv[i] * sum_k X[i][k] W[k][j] ), wlds passed in (LDS union).
// mfma_f32_16x16x32_f16: A[m=lane&15][k=quad*8+j]; B[k=quad*8+j][n=lane&15];
// D: row=quad*4+reg, col=lane&15. Pitch 136 halves: 16B-aligned, 2-way banks (free).

template<bool F32IN>
__device__ __forceinline__ void gemm_body512(
    const void* __restrict__ Xv, const __half* __restrict__ WT,
    const float* __restrict__ dinv, __half* __restrict__ out, int M, int bid,
    __half (*wlds)[136])
{
    const int tid = threadIdx.x;
    {   // stage WT (128x128 halves): 4 threads/row, 32 halves (4 x half8) each
        int r = tid >> 2;
        int c0 = (tid & 3) * 32;
        const half8* s = (const half8*)(WT + (size_t)r * NF + c0);
        half8* d = (half8*)&wlds[r][c0];
        #pragma unroll
        for (int j = 0; j < 4; j++) d[j] = s[j];
    }
    __syncthreads();

    const int wave = tid >> 6, lane = tid & 63;
    const int quad = lane >> 4, l15 = lane & 15;
    const int rowA = bid * 128 + wave * 16 + l15;
    const int rowc = (rowA < M) ? rowA : (M - 1);   // clamp (dup row, never stored)

    half8 afr[4];
    if (F32IN) {
        const float* X = (const float*)Xv;
        #pragma unroll
        for (int kc = 0; kc < 4; kc++) {
            const floatx4* p = (const floatx4*)(X + (size_t)rowc * NF + kc * 32 + quad * 8);
            floatx4 u = p[0], v = p[1];
            half8 a;
            a[0] = (_Float16)u[0]; a[1] = (_Float16)u[1];
            a[2] = (_Float16)u[2]; a[3] = (_Float16)u[3];
            a[4] = (_Float16)v[0]; a[5] = (_Float16)v[1];
            a[6] = (_Float16)v[2]; a[7] = (_Float16)v[3];
            afr[kc] = a;
        }
    } else {
        const __half* X = (const __half*)Xv;
        #pragma unroll
        for (int kc = 0; kc < 4; kc++)
            afr[kc] = *(const half8*)(X + (size_t)rowc * NF + kc * 32 + quad * 8);
    }

    floatx4 acc[8];
    #pragma unroll
    for (int ct = 0; ct < 8; ct++) { floatx4 z = {0.f, 0.f, 0.f, 0.f}; acc[ct] = z; }

    #pragma unroll
    for (int kc = 0; kc < 4; kc++) {
        #pragma unroll
        for (int ct = 0; ct < 8; ct++) {
            half8 b = *(const half8*)&wlds[ct * 16 + l15][kc * 32 + quad * 8];
            acc[ct] = __builtin_amdgcn_mfma_f32_16x16x32_f16(afr[kc], b, acc[ct], 0, 0, 0);
        }
    }

    const int orow0 = bid * 128 + wave * 16 + quad * 4;
    #pragma unroll
    for (int r = 0; r < 4; r++) {
        int orow = orow0 + r;
        if (orow < M) {
            float s = dinv[orow];
            #pragma unroll
            for (int ct = 0; ct < 8; ct++)
                out[(size_t)orow * NF + ct * 16 + l15] = __float2half(acc[ct][r] * s);
        }
    }
}

// ---------------- mid_k: fused gemm1 + fill (+add_off) ---------------------------
// Blocks [0,GB2): layer-1 GEMM (512 thr, 128 rows). Blocks >= GB2: CSR fill with
// LDS cursor; each fill block scans blocksum itself (exclusive prefix in LDS) so
// add_off2 is gone; c==0 blocks emit corrected rowptr2 (coff[0]==0), and agg
// uses rowptr2. LDS is a union: max(gemm 34KB, fill 50KB+1KB) = 51.2KB.
__global__ __launch_bounds__(512) void mid_k(
    const int* __restrict__ src, const int* __restrict__ dst,
    const int* __restrict__ rowptr, const unsigned short* __restrict__ coff,
    const int* __restrict__ blocksum, int* __restrict__ rowptr2,
    int* __restrict__ csr, int E, int N, int Ec, int nb,
    const float* __restrict__ X, const __half* __restrict__ WT,
    const float* __restrict__ dinv, __half* __restrict__ H, int GB2)
{
    __shared__ __align__(16) char smem[NPMAX * 4 + 1024];   // 51.2KB union
    const int tid = threadIdx.x;
    if ((int)blockIdx.x < GB2) {
        gemm_body512<true>(X, WT, dinv, H, N, blockIdx.x, (__half(*)[136])smem);
        return;
    }
    int* lcur = (int*)smem;
    int* pref = (int*)(smem + NPMAX * 4);

    const int b = blockIdx.x - GB2;
    const int p = b & 3, c = b >> 2;
    const int Np = (N + 3) >> 2;
    const int lo = p * Np, hi = min(lo + Np, N);
    const int sz = hi - lo;

    // exclusive prefix of blocksum[0..nb) in pref (Hillis-Steele, 256 wide)
    int v = (tid < nb) ? blocksum[tid] : 0;
    if (tid < 256) pref[tid] = v;
    __syncthreads();
    #pragma unroll
    for (int d = 1; d < 256; d <<= 1) {
        int t = (tid < 256 && tid >= d) ? pref[tid - d] : 0;
        __syncthreads();
        if (tid < 256) pref[tid] += t;
        __syncthreads();
    }
    if (tid < 256) pref[tid] -= v;   // inclusive -> exclusive
    __syncthreads();

    for (int i = tid; i < sz; i += 512) {
        int bin = lo + i;
        int r = rowptr[bin] + pref[bin >> 8] + (int)coff[(size_t)c * N + bin];
        lcur[i] = r;
        if (c == 0) rowptr2[bin] = r;   // coff[0][bin] == 0 -> corrected rowptr
    }
    if (c == 0 && p == 0 && tid == 0) rowptr2[N] = E;
    __syncthreads();

    const int e0 = c * Ec, e1 = min(e0 + Ec, E);
    for (int e = e0 + tid * 4; e + 3 < e1; e += 512 * 4) {
        int4 d = *(const int4*)(dst + e);
        int4 s = *(const int4*)(src + e);
        if (d.x >= lo && d.x < hi) csr[atomicAdd(&lcur[d.x - lo], 1)] = s.x;
        if (d.y >= lo && d.y < hi) csr[atomicAdd(&lcur[d.y - lo], 1)] = s.y;
        if (d.z >= lo && d.z < hi) csr[atomicAdd(&lcur[d.z - lo], 1)] = s.z;
        if (d.w >= lo && d.w < hi) csr[atomicAdd(&lcur[d.w - lo], 1)] = s.w;
    }
    int rem0 = e0 + ((e1 - e0) & ~3);
    for (int e = rem0 + tid; e < e1; e += 512) {
        int d = dst[e];
        if (d >= lo && d < hi) csr[atomicAdd(&lcur[d - lo], 1)] = src[e];
    }
}

// ---------------- gemm2 (standalone, 256 thr / 64 rows — proven R8 shape) --------
template<bool F32IN>
__device__ __forceinline__ void gemm_body256(
    const void* __restrict__ Xv, const __half* __restrict__ WT,
    const float* __restrict__ dinv, __half* __restrict__ out, int M, int bid)
{
    __shared__ __half wlds[128][136];
    const int tid = threadIdx.x;
    {
        int r = tid >> 1;
        int c0 = (tid & 1) * 64;
        const half8* s = (const half8*)(WT + (size_t)r * NF + c0);
        half8* d = (half8*)&wlds[r][c0];
        #pragma unroll
        for (int j = 0; j < 8; j++) d[j] = s[j];
    }
    __syncthreads();

    const int wave = tid >> 6, lane = tid & 63;
    const int quad = lane >> 4, l15 = lane & 15;
    const int rowA = bid * 64 + wave * 16 + l15;
    const int rowc = (rowA < M) ? rowA : (M - 1);

    half8 afr[4];
    const __half* X = (const __half*)Xv;
    #pragma unroll
    for (int kc = 0; kc < 4; kc++)
        afr[kc] = *(const half8*)(X + (size_t)rowc * NF + kc * 32 + quad * 8);

    floatx4 acc[8];
    #pragma unroll
    for (int ct = 0; ct < 8; ct++) { floatx4 z = {0.f, 0.f, 0.f, 0.f}; acc[ct] = z; }

    #pragma unroll
    for (int kc = 0; kc < 4; kc++) {
        #pragma unroll
        for (int ct = 0; ct < 8; ct++) {
            half8 b = *(const half8*)&wlds[ct * 16 + l15][kc * 32 + quad * 8];
            acc[ct] = __builtin_amdgcn_mfma_f32_16x16x32_f16(afr[kc], b, acc[ct], 0, 0, 0);
        }
    }

    const int orow0 = bid * 64 + wave * 16 + quad * 4;
    #pragma unroll
    for (int r = 0; r < 4; r++) {
        int orow = orow0 + r;
        if (orow < M) {
            float s = dinv[orow];
            #pragma unroll
            for (int ct = 0; ct < 8; ct++)
                out[(size_t)orow * NF + ct * 16 + l15] = __float2half(acc[ct][r] * s);
        }
    }
}

__global__ __launch_bounds__(256) void gemm2_k(
    const __half* __restrict__ A, const __half* __restrict__ WT,
    const float* __restrict__ dinv, __half* __restrict__ H, int M)
{
    gemm_body256<false>(A, WT, dinv, H, M, blockIdx.x);
}

// ---------------- Aggregation: wave/node, 2 rows per gather instruction ----------
// lane = half4 (8B), 32 lanes/row; eg=lane>>5 picks edge parity -> each load
// instruction fetches TWO src rows (512B). Per 16 edges: 8 loads + 8 bpermutes
// (vs 16+16 in the 1-row form), same bytes in flight. Final shfl_xor(32) folds
// the two edge sets. acc = self + sum_in; res = dinv*acc + bias.

__global__ __launch_bounds__(256) void agg_k(
    const __half* __restrict__ hs, const int* __restrict__ rowptr,
    const int* __restrict__ csr, const float* __restrict__ dinv,
    const float* __restrict__ bias, __half* __restrict__ outh,
    float* __restrict__ outf, int n)
{
    int wave = threadIdx.x >> 6;
    int lane = threadIdx.x & 63;
    int node = blockIdx.x * 4 + wave;
    if (node >= n) return;
    const int eg = lane >> 5, fl = lane & 31;

    const half4v* hs4 = (const half4v*)hs;   // 32 half4 per row
    floatx4 acc = {0.f, 0.f, 0.f, 0.f};
    if (eg == 0) {
        half4v s = hs4[(size_t)node * 32 + fl];
        acc[0] = (float)s[0]; acc[1] = (float)s[1];
        acc[2] = (float)s[2]; acc[3] = (float)s[3];
    }

    int base = rowptr[node];
    int cnt  = rowptr[node + 1] - base;

    for (int off = 0; off < cnt; off += 64) {
        int m = min(64, cnt - off);
        int idx = 0;
        if (lane < m) idx = __builtin_nontemporal_load(&csr[base + off + lane]);
        for (int j = 0; j < m; j += 16) {   // 16 edges per iter, 8 loads deep
            int s[8];
            half4v v[8];
            #pragma unroll
            for (int t = 0; t < 8; t++)
                s[t] = __shfl(idx, min(j + 2 * t + eg, m - 1), 64);
            #pragma unroll
            for (int t = 0; t < 8; t++)
                v[t] = hs4[(size_t)s[t] * 32 + fl];
            #pragma unroll
            for (int t = 0; t < 8; t++) {
                if (j + 2 * t + eg < m) {
                    acc[0] += (float)v[t][0]; acc[1] += (float)v[t][1];
                    acc[2] += (float)v[t][2]; acc[3] += (float)v[t][3];
                }
            }
        }
    }

    // fold the two edge sets (lanes l and l^32)
    #pragma unroll
    for (int k = 0; k < 4; k++) acc[k] += __shfl_xor(acc[k], 32, 64);

    if (eg == 0) {
        float dv = dinv[node];
        float o0 = dv * acc[0] + bias[fl * 4];
        float o1 = dv * acc[1] + bias[fl * 4 + 1];
        float o2 = dv * acc[2] + bias[fl * 4 + 2];
        float o3 = dv * acc[3] + bias[fl * 4 + 3];
        if (outh) {
            half4v h;
            h[0] = (_Float16)fmaxf(o0, 0.f); h[1] = (_Float16)fmaxf(o1, 0.f);
            h[2] = (_Float16)fmaxf(o2, 0.f); h[3] = (_Float16)fmaxf(o3, 0.f);
            *(half4v*)&outh[(size_t)node * NF + fl * 4] = h;
        } else {
            floatx4 w = {o0, o1, o2, o3};
            *(floatx4*)(outf + (size_t)node * NF + fl * 4) = w;
        }
    }
}

// ---------------- launch ----------------

extern "C" void kernel_launch(void* const* d_in, const int* in_sizes, int n_in,
                              void* d_out, int out_size, void* d_ws, size_t ws_size,
                              hipStream_t stream) {
    const float* x  = (const float*)d_in[0];
    const int*   ei = (const int*)d_in[1];
    const float* W1 = (const float*)d_in[2];
    const float* b1 = (const float*)d_in[3];
    const float* W2 = (const float*)d_in[4];
    const float* b2 = (const float*)d_in[5];
    float* out = (float*)d_out;

    const int N = in_sizes[0] / NF;   // 50000
    const int E = in_sizes[1] / 2;    // 800000
    const int* src = ei;
    const int* dst = ei + E;

    char* ws = (char*)d_ws;
    size_t off = 0;
    auto alloc = [&](size_t bytes) {
        void* p = ws + off;
        off += bytes;
        off = (off + 63) & ~(size_t)63;
        return p;
    };
    unsigned short* pcnt = (unsigned short*)alloc((size_t)KC * N * 2);  // counts->coff
    int*    rowptr  = (int*)alloc((size_t)(N + 1) * 4);   // local prefixes
    int*    rowptr2 = (int*)alloc((size_t)(N + 1) * 4);   // corrected (agg uses)
    int*    csr     = (int*)alloc((size_t)E * 4);
    float*  dinv    = (float*)alloc((size_t)N * 4);
    int*    bsum    = (int*)alloc((size_t)256 * 4);
    __half* WT1     = (__half*)alloc((size_t)NF * NF * 2);
    __half* WT2     = (__half*)alloc((size_t)NF * NF * 2);
    __half* H16     = (__half*)alloc((size_t)N * NF * 2);
    __half* A16     = (__half*)alloc((size_t)N * NF * 2);

    int nb  = (N + 255) / 256;                 // 196 (<=256)
    int Ec  = (((E + KC - 1) / KC) + 3) & ~3;  // chunk size, multiple of 4
    int GB2 = (N + 127) / 128;                 // 391 gemm1 blocks (512 thr)
    int gb  = (N + 63) / 64;
    int ab  = (N + 3) / 4;

    count2_k<<<KC * NPART, 512, 0, stream>>>(dst, pcnt, E, N, Ec);
    pscan2_k<<<nb + 128, 256, 0, stream>>>(pcnt, dinv, rowptr, bsum, N, N, nb,
                                           W1, W2, WT1, WT2);
    mid_k<<<GB2 + KC * NPART, 512, 0, stream>>>(src, dst, rowptr, pcnt, bsum,
                                                rowptr2, csr, E, N, Ec, nb,
                                                x, WT1, dinv, H16, GB2);
    agg_k<<<ab, 256, 0, stream>>>(H16, rowptr2, csr, dinv, b1, A16, nullptr, N);
    gemm2_k<<<gb, 256, 0, stream>>>(A16, WT2, dinv, H16, N);
    agg_k<<<ab, 256, 0, stream>>>(H16, rowptr2, csr, dinv, b2, nullptr, out, N);
}